// Round 1
// baseline (166.040 us; speedup 1.0000x reference)
//
#include <hip/hip_runtime.h>
#include <math.h>

#define NQ   10
#define DIM  1024
#define NBL  4
#define VDL  6
#define NOBS 9
#define LATD 128

// ---------------- circuit helpers ----------------

__device__ __forceinline__ float wave_reduce_sum(float x) {
#pragma unroll
  for (int m = 32; m >= 1; m >>= 1) x += __shfl_xor(x, m, 64);
  return x;
}

// RY on a register-bit qubit (bit 9..6 of amp index -> reg bits 3..0)
template<int M>
__device__ __forceinline__ void ry_reg(float v[16], float c, float s) {
#pragma unroll
  for (int r = 0; r < 16; ++r) {
    if ((r & M) == 0) {
      float p0 = v[r], p1 = v[r | M];
      v[r]     = c * p0 - s * p1;
      v[r | M] = s * p0 + c * p1;
    }
  }
}

// RY on a lane-bit qubit (bit 5..0 of amp index = lane bit)
template<int MASK>
__device__ __forceinline__ void ry_lane(float v[16], float c, float s, int lane) {
  float sp = (lane & MASK) ? s : -s;
#pragma unroll
  for (int r = 0; r < 16; ++r) {
    float p = __shfl_xor(v[r], MASK, 64);
    v[r] = c * v[r] + sp * p;
  }
}

// CNOT where both ctrl and tgt are lane bits: pure lane permutation
template<int CBIT, int TBIT>
__device__ __forceinline__ void cnot_lane(float v[16], int lane) {
  int src = (lane & CBIT) ? (lane ^ TBIT) : lane;
#pragma unroll
  for (int r = 0; r < 16; ++r) v[r] = __shfl(v[r], src, 64);
}

__device__ __forceinline__ void apply_rys(float v[16], int lane, const float* __restrict__ ang) {
  float c, s;
  sincosf(0.5f * ang[0], &s, &c); ry_reg<8>(v, c, s);
  sincosf(0.5f * ang[1], &s, &c); ry_reg<4>(v, c, s);
  sincosf(0.5f * ang[2], &s, &c); ry_reg<2>(v, c, s);
  sincosf(0.5f * ang[3], &s, &c); ry_reg<1>(v, c, s);
  sincosf(0.5f * ang[4], &s, &c); ry_lane<32>(v, c, s, lane);
  sincosf(0.5f * ang[5], &s, &c); ry_lane<16>(v, c, s, lane);
  sincosf(0.5f * ang[6], &s, &c); ry_lane<8>(v, c, s, lane);
  sincosf(0.5f * ang[7], &s, &c); ry_lane<4>(v, c, s, lane);
  sincosf(0.5f * ang[8], &s, &c); ry_lane<2>(v, c, s, lane);
  sincosf(0.5f * ang[9], &s, &c); ry_lane<1>(v, c, s, lane);
}

__device__ __forceinline__ void cnot_ladder(float v[16], int lane) {
  float t;
  // even: ctrl=0 (reg bit3 -> reg bit2)
  t=v[8];  v[8]=v[12];  v[12]=t;
  t=v[9];  v[9]=v[13];  v[13]=t;
  t=v[10]; v[10]=v[14]; v[14]=t;
  t=v[11]; v[11]=v[15]; v[15]=t;
  // ctrl=2 (reg bit1 -> reg bit0)
  t=v[2];  v[2]=v[3];   v[3]=t;
  t=v[6];  v[6]=v[7];   v[7]=t;
  t=v[10]; v[10]=v[11]; v[11]=t;
  t=v[14]; v[14]=v[15]; v[15]=t;
  cnot_lane<32,16>(v, lane); // ctrl=4
  cnot_lane<8,4>(v, lane);   // ctrl=6
  cnot_lane<2,1>(v, lane);   // ctrl=8
  // odd: ctrl=1 (reg bit2 -> reg bit1)
  t=v[4];  v[4]=v[6];   v[6]=t;
  t=v[5];  v[5]=v[7];   v[7]=t;
  t=v[12]; v[12]=v[14]; v[14]=t;
  t=v[13]; v[13]=v[15]; v[15]=t;
  // ctrl=3: ctrl = reg bit0, tgt = lane bit5
#pragma unroll
  for (int r = 1; r < 16; r += 2) v[r] = __shfl_xor(v[r], 32, 64);
  cnot_lane<16,8>(v, lane);  // ctrl=5
  cnot_lane<4,2>(v, lane);   // ctrl=7
}

// ---------------- kernels ----------------

// x = [z, cos(t*f), sin(t*f)]; h = silu(x@W1+b1); enc = h@W2+b2
__global__ __launch_bounds__(256) void enc_kernel(
    const float* __restrict__ z, const float* __restrict__ t,
    const float* __restrict__ W1, const float* __restrict__ b1,
    const float* __restrict__ W2, const float* __restrict__ b2,
    float* __restrict__ enc) {
  __shared__ float xs[256];
  __shared__ float hs[256];
  int b = blockIdx.x;
  int tid = threadIdx.x;
  if (tid < LATD) {
    xs[tid] = z[b * LATD + tid];
  } else {
    int i = tid - LATD;        // 0..127
    int j = i & 63;            // freq index
    float freq = expf(-logf(10000.f) * (float)j * (1.0f / 64.0f));
    float arg = t[b] * freq;
    xs[tid] = (i < 64) ? cosf(arg) : sinf(arg);
  }
  __syncthreads();
  float acc = b1[tid];
  for (int i = 0; i < 256; ++i) acc = fmaf(xs[i], W1[i * 256 + tid], acc);
  acc = acc / (1.f + expf(-acc));     // silu
  hs[tid] = acc;
  __syncthreads();
  if (tid < NBL * NQ) {
    float a2 = b2[tid];
    for (int j = 0; j < 256; ++j) a2 = fmaf(hs[j], W2[j * (NBL * NQ) + tid], a2);
    enc[b * (NBL * NQ) + tid] = a2;
  }
}

// one wave per batch element; real statevector in registers
__global__ __launch_bounds__(256) void circuit_kernel(
    const float* __restrict__ enc, const float* __restrict__ varp,
    const float* __restrict__ A_p, const float* __restrict__ D_p,
    float* __restrict__ obs, int Btot) {
  __shared__ float st[4 * DIM];
  int wave = threadIdx.x >> 6;
  int lane = threadIdx.x & 63;
  int b = blockIdx.x * 4 + wave;
  if (b >= Btot) return;

  float v[16];
#pragma unroll
  for (int r = 0; r < 16; ++r) v[r] = 0.f;
  if (lane == 0) v[0] = 1.f;

  const float* eb = enc + b * (NBL * NQ);
#pragma unroll 1
  for (int layer = 0; layer < NBL; ++layer) {
    apply_rys(v, lane, eb + layer * NQ);
    if (layer < NBL - 1) cnot_ladder(v, lane);
  }
#pragma unroll 1
  for (int ly = 0; ly < VDL; ++ly) {
    apply_rys(v, lane, varp + ly * NQ);
    cnot_ladder(v, lane);
  }

  // dump this wave's state to its private LDS region (no cross-wave sharing)
  float* sw = st + wave * DIM;
#pragma unroll
  for (int r = 0; r < 16; ++r) sw[r * 64 + lane] = v[r];

  // expectation values: obs s acts on qubit pair (s, s+1) -> bits (9-s, 8-s)
#pragma unroll 1
  for (int s = 0; s < NOBS; ++s) {
    int r8 = 8 - s;
    int stride = 1 << r8;
    float h10 = A_p[s*6+0], h20 = A_p[s*6+1], h21 = A_p[s*6+2];
    float h30 = A_p[s*6+3], h31 = A_p[s*6+4], h32 = A_p[s*6+5];
    float d0 = 2.f * D_p[s*4+1], d1 = 2.f * D_p[s*4+2], d2 = 2.f * D_p[s*4+3];
    float acc = 0.f;
#pragma unroll
    for (int k = 0; k < 4; ++k) {
      int p = lane + 64 * k;          // 256 (a,r) pairs total
      int a  = p >> r8;
      int rr = p & (stride - 1);
      int base = (a << (r8 + 2)) + rr;
      float x0 = sw[base];
      float x1 = sw[base + stride];
      float x2 = sw[base + 2 * stride];
      float x3 = sw[base + 3 * stride];
      acc += d0 * x0 * x0 + d1 * x1 * x1 + d2 * x2 * x2
           + 2.f * (h10 * x1 * x0 + h20 * x2 * x0 + h21 * x2 * x1
                  + h30 * x3 * x0 + h31 * x3 * x1 + h32 * x3 * x2);
    }
    acc = wave_reduce_sum(acc);
    if (lane == 0) obs[b * NOBS + s] = acc;
  }
}

// out = silu(obs@W3+b3) @ W4 + b4
__global__ __launch_bounds__(256) void head_kernel(
    const float* __restrict__ obs, const float* __restrict__ W3,
    const float* __restrict__ b3, const float* __restrict__ W4,
    const float* __restrict__ b4, float* __restrict__ out) {
  __shared__ float os[NOBS];
  __shared__ float hs[256];
  int b = blockIdx.x;
  int tid = threadIdx.x;
  if (tid < NOBS) os[tid] = obs[b * NOBS + tid];
  __syncthreads();
  float acc = b3[tid];
#pragma unroll
  for (int s = 0; s < NOBS; ++s) acc = fmaf(os[s], W3[s * 256 + tid], acc);
  acc = acc / (1.f + expf(-acc));
  hs[tid] = acc;
  __syncthreads();
  if (tid < LATD) {
    float a = b4[tid];
    for (int j = 0; j < 256; ++j) a = fmaf(hs[j], W4[j * LATD + tid], a);
    out[b * LATD + tid] = a;
  }
}

// ---------------- launcher ----------------

extern "C" void kernel_launch(void* const* d_in, const int* in_sizes, int n_in,
                              void* d_out, int out_size, void* d_ws, size_t ws_size,
                              hipStream_t stream) {
  const float* z_t  = (const float*)d_in[0];
  const float* t    = (const float*)d_in[1];
  const float* W1   = (const float*)d_in[2];
  const float* b1   = (const float*)d_in[3];
  const float* W2   = (const float*)d_in[4];
  const float* b2   = (const float*)d_in[5];
  const float* varp = (const float*)d_in[6];
  const float* A_p  = (const float*)d_in[7];
  // d_in[8] = B_p: imaginary part of H — contributes 0 to <psi|H|psi> for real psi
  const float* D_p  = (const float*)d_in[9];
  const float* W3   = (const float*)d_in[10];
  const float* b3   = (const float*)d_in[11];
  const float* W4   = (const float*)d_in[12];
  const float* b4   = (const float*)d_in[13];
  float* out = (float*)d_out;

  int B = in_sizes[1];  // t has one element per batch row

  float* enc = (float*)d_ws;          // B * 40
  float* obs = enc + (size_t)B * 40;  // B * 9

  enc_kernel<<<B, 256, 0, stream>>>(z_t, t, W1, b1, W2, b2, enc);
  circuit_kernel<<<(B + 3) / 4, 256, 0, stream>>>(enc, varp, A_p, D_p, obs, B);
  head_kernel<<<B, 256, 0, stream>>>(obs, W3, b3, W4, b4, out);
}

// Round 2
// 132.086 us; speedup vs baseline: 1.2571x; 1.2571x over previous
//
#include <hip/hip_runtime.h>
#include <math.h>

#define NQ   10
#define DIM  1024
#define NOBS 9
#define LATD 128

__device__ __forceinline__ float silu_f(float x) { return x / (1.f + expf(-x)); }

// ---------------- DPP lane-exchange helpers (VALU, not DS pipe) ----------------
// quad_perm(1,0,3,2)=0xB1 -> xor1 ; quad_perm(2,3,0,1)=0x4E -> xor2 ; row_ror:8=0x128 -> xor8
template<int CTRL>
__device__ __forceinline__ float dpp_perm(float x) {
  return __int_as_float(__builtin_amdgcn_update_dpp(0, __float_as_int(x), CTRL, 0xF, 0xF, true));
}

// ---------------- circuit helpers ----------------

__device__ __forceinline__ float wave_reduce_sum(float x) {
#pragma unroll
  for (int m = 32; m >= 1; m >>= 1) x += __shfl_xor(x, m, 64);
  return x;
}

// RY on a register-bit qubit (amp bits 9..6 -> reg bits 3..0)
template<int M>
__device__ __forceinline__ void ry_reg(float v[16], float c, float s) {
#pragma unroll
  for (int r = 0; r < 16; ++r) {
    if ((r & M) == 0) {
      float p0 = v[r], p1 = v[r | M];
      v[r]     = c * p0 - s * p1;
      v[r | M] = s * p0 + c * p1;
    }
  }
}

// RY on a lane-bit qubit via ds_bpermute (__shfl_xor)
template<int MASK>
__device__ __forceinline__ void ry_lane(float v[16], float c, float s, int lane) {
  float sp = (lane & MASK) ? s : -s;
#pragma unroll
  for (int r = 0; r < 16; ++r) {
    float p = __shfl_xor(v[r], MASK, 64);
    v[r] = c * v[r] + sp * p;
  }
}

// RY on a lane-bit qubit via DPP (masks 1,2,8)
template<int CTRL, int MASK>
__device__ __forceinline__ void ry_lane_dpp(float v[16], float c, float s, int lane) {
  float sp = (lane & MASK) ? s : -s;
#pragma unroll
  for (int r = 0; r < 16; ++r) {
    float p = dpp_perm<CTRL>(v[r]);
    v[r] = c * v[r] + sp * p;
  }
}

__device__ __forceinline__ void apply_rys(float v[16], int lane,
                                          const float* __restrict__ cc,
                                          const float* __restrict__ ss) {
  ry_reg<8>(v, cc[0], ss[0]);
  ry_reg<4>(v, cc[1], ss[1]);
  ry_reg<2>(v, cc[2], ss[2]);
  ry_reg<1>(v, cc[3], ss[3]);
  ry_lane<32>(v, cc[4], ss[4], lane);
  ry_lane<16>(v, cc[5], ss[5], lane);
  ry_lane_dpp<0x128, 8>(v, cc[6], ss[6], lane);
  ry_lane<4>(v, cc[7], ss[7], lane);
  ry_lane_dpp<0x4E, 2>(v, cc[8], ss[8], lane);
  ry_lane_dpp<0xB1, 1>(v, cc[9], ss[9], lane);
}

// CNOT ladder: evens (ctrl 0,2 reg; 4,6,8 lane fused into one perm),
// then odds (ctrl 1 reg; 3 mixed + 5,7 lane fused into one perm).
__device__ __forceinline__ void cnot_ladder(float v[16], int lane) {
  float t;
  // ctrl0: reg bit3 -> bit2
  t=v[8];  v[8]=v[12];  v[12]=t;
  t=v[9];  v[9]=v[13];  v[13]=t;
  t=v[10]; v[10]=v[14]; v[14]=t;
  t=v[11]; v[11]=v[15]; v[15]=t;
  // ctrl2: reg bit1 -> bit0
  t=v[2];  v[2]=v[3];   v[3]=t;
  t=v[6];  v[6]=v[7];   v[7]=t;
  t=v[10]; v[10]=v[11]; v[11]=t;
  t=v[14]; v[14]=v[15]; v[15]=t;
  // fused lane CNOTs (4,5),(6,7),(8,9): src = lane ^ ((lane&0b101010)>>1)
  int se = lane ^ ((lane & 42) >> 1);
#pragma unroll
  for (int r = 0; r < 16; ++r) v[r] = __shfl(v[r], se, 64);
  // ctrl1: reg bit2 -> bit1
  t=v[4];  v[4]=v[6];   v[6]=t;
  t=v[5];  v[5]=v[7];   v[7]=t;
  t=v[12]; v[12]=v[14]; v[14]=t;
  t=v[13]; v[13]=v[15]; v[15]=t;
  // fused (5,6),(7,8) lane perm + (3,4) mixed (reg bit0 ctrl -> lane bit 32 tgt)
  int so  = lane ^ ((lane & 20) >> 1);
  int so1 = so ^ 32;
#pragma unroll
  for (int r = 0; r < 16; ++r) v[r] = __shfl(v[r], (r & 1) ? so1 : so, 64);
}

// ---------------- kernels ----------------

// var-layer cos/sin precompute (60 angles)
__global__ __launch_bounds__(64) void varcs_kernel(const float* __restrict__ varp,
                                                   float* __restrict__ varc,
                                                   float* __restrict__ vars) {
  int tid = threadIdx.x;
  if (tid < 60) {
    float s, c;
    sincosf(0.5f * varp[tid], &s, &c);
    varc[tid] = c;
    vars[tid] = s;
  }
}

// 4 rows/block: x=[z, cos, sin]; h=silu(x@W1+b1); ang=h@W2+b2; store cos/sin(ang/2)
__global__ __launch_bounds__(256) void enc_kernel(
    const float* __restrict__ z, const float* __restrict__ t,
    const float* __restrict__ W1, const float* __restrict__ b1,
    const float* __restrict__ W2, const float* __restrict__ b2,
    float* __restrict__ encc, float* __restrict__ encs) {
  __shared__ float xs[4][256];
  __shared__ float hs[4][256];
  int tid = threadIdx.x;
  int b0 = blockIdx.x * 4;
#pragma unroll
  for (int r = 0; r < 4; ++r) {
    int b = b0 + r;
    if (tid < 128) {
      xs[r][tid] = z[b * 128 + tid];
    } else {
      int i = tid - 128, j = i & 63;
      float freq = expf(-9.2103403719761836f * (float)j * (1.f / 64.f));
      float arg = t[b] * freq;
      xs[r][tid] = (i < 64) ? cosf(arg) : sinf(arg);
    }
  }
  __syncthreads();
  float bv = b1[tid];
  float a0 = bv, a1 = bv, a2 = bv, a3 = bv;
  for (int k = 0; k < 256; k += 4) {
    float w0 = W1[(k + 0) * 256 + tid];
    float w1 = W1[(k + 1) * 256 + tid];
    float w2 = W1[(k + 2) * 256 + tid];
    float w3 = W1[(k + 3) * 256 + tid];
    float4 x0 = *(const float4*)&xs[0][k];
    float4 x1 = *(const float4*)&xs[1][k];
    float4 x2 = *(const float4*)&xs[2][k];
    float4 x3 = *(const float4*)&xs[3][k];
    a0 = fmaf(x0.w, w3, fmaf(x0.z, w2, fmaf(x0.y, w1, fmaf(x0.x, w0, a0))));
    a1 = fmaf(x1.w, w3, fmaf(x1.z, w2, fmaf(x1.y, w1, fmaf(x1.x, w0, a1))));
    a2 = fmaf(x2.w, w3, fmaf(x2.z, w2, fmaf(x2.y, w1, fmaf(x2.x, w0, a2))));
    a3 = fmaf(x3.w, w3, fmaf(x3.z, w2, fmaf(x3.y, w1, fmaf(x3.x, w0, a3))));
  }
  hs[0][tid] = silu_f(a0);
  hs[1][tid] = silu_f(a1);
  hs[2][tid] = silu_f(a2);
  hs[3][tid] = silu_f(a3);
  __syncthreads();
  if (tid < 160) {
    int r = tid / 40, c = tid - r * 40;
    float acc = b2[c];
    for (int k = 0; k < 256; k += 4) {
      float4 h = *(const float4*)&hs[r][k];
      acc = fmaf(h.x, W2[(k + 0) * 40 + c], acc);
      acc = fmaf(h.y, W2[(k + 1) * 40 + c], acc);
      acc = fmaf(h.z, W2[(k + 2) * 40 + c], acc);
      acc = fmaf(h.w, W2[(k + 3) * 40 + c], acc);
    }
    int b = b0 + r;
    float s, cv;
    sincosf(0.5f * acc, &s, &cv);
    encc[b * 40 + c] = cv;
    encs[b * 40 + c] = s;
  }
}

// one 64-thread block per batch element; real statevector in registers
__global__ __launch_bounds__(64) void circuit_kernel(
    const float* __restrict__ encc, const float* __restrict__ encs,
    const float* __restrict__ varc, const float* __restrict__ vars,
    const float* __restrict__ A_p, const float* __restrict__ D_p,
    float* __restrict__ obs) {
  __shared__ float sw[DIM];
  int lane = threadIdx.x;
  int b = blockIdx.x;
  const float* cc = encc + b * 40;
  const float* ss = encs + b * 40;

  // layer 0 on |0..0> is a product state: amp(bit pattern) = prod (bit ? s : c)
  float base = 1.f;
  base *= (lane & 32) ? ss[4] : cc[4];
  base *= (lane & 16) ? ss[5] : cc[5];
  base *= (lane & 8)  ? ss[6] : cc[6];
  base *= (lane & 4)  ? ss[7] : cc[7];
  base *= (lane & 2)  ? ss[8] : cc[8];
  base *= (lane & 1)  ? ss[9] : cc[9];
  float v[16];
#pragma unroll
  for (int r = 0; r < 16; ++r) {
    float p = base;
    p *= (r & 8) ? ss[0] : cc[0];
    p *= (r & 4) ? ss[1] : cc[1];
    p *= (r & 2) ? ss[2] : cc[2];
    p *= (r & 1) ? ss[3] : cc[3];
    v[r] = p;
  }
  cnot_ladder(v, lane);
#pragma unroll 1
  for (int layer = 1; layer < 4; ++layer) {
    apply_rys(v, lane, cc + layer * 10, ss + layer * 10);
    if (layer < 3) cnot_ladder(v, lane);
  }
#pragma unroll 1
  for (int ly = 0; ly < 6; ++ly) {
    apply_rys(v, lane, varc + ly * 10, vars + ly * 10);
    cnot_ladder(v, lane);
  }

#pragma unroll
  for (int r = 0; r < 16; ++r) sw[r * 64 + lane] = v[r];

#pragma unroll
  for (int s = 0; s < NOBS; ++s) {
    const int r8 = 8 - s;
    const int stride = 1 << r8;
    float h10 = A_p[s*6+0], h20 = A_p[s*6+1], h21 = A_p[s*6+2];
    float h30 = A_p[s*6+3], h31 = A_p[s*6+4], h32 = A_p[s*6+5];
    float d0 = 2.f * D_p[s*4+1], d1 = 2.f * D_p[s*4+2], d2 = 2.f * D_p[s*4+3];
    float acc = 0.f;
#pragma unroll
    for (int k = 0; k < 4; ++k) {
      int p = lane + 64 * k;
      int a  = p >> r8;
      int rr = p & (stride - 1);
      int bse = (a << (r8 + 2)) + rr;
      float x0 = sw[bse];
      float x1 = sw[bse + stride];
      float x2 = sw[bse + 2 * stride];
      float x3 = sw[bse + 3 * stride];
      acc += d0 * x0 * x0 + d1 * x1 * x1 + d2 * x2 * x2
           + 2.f * (h10 * x1 * x0 + h20 * x2 * x0 + h21 * x2 * x1
                  + h30 * x3 * x0 + h31 * x3 * x1 + h32 * x3 * x2);
    }
    acc = wave_reduce_sum(acc);
    if (lane == 0) obs[b * NOBS + s] = acc;
  }
}

// 4 rows/block: out = silu(obs@W3+b3) @ W4 + b4
__global__ __launch_bounds__(256) void head_kernel(
    const float* __restrict__ obs, const float* __restrict__ W3,
    const float* __restrict__ b3, const float* __restrict__ W4,
    const float* __restrict__ b4, float* __restrict__ out) {
  __shared__ float os[4][NOBS];
  __shared__ float hs[4][256];
  int tid = threadIdx.x;
  int b0 = blockIdx.x * 4;
  if (tid < 4 * NOBS) os[tid / NOBS][tid % NOBS] = obs[b0 * NOBS + tid];
  __syncthreads();
  float bv = b3[tid];
  float a0 = bv, a1 = bv, a2 = bv, a3 = bv;
#pragma unroll
  for (int s = 0; s < NOBS; ++s) {
    float w = W3[s * 256 + tid];
    a0 = fmaf(os[0][s], w, a0);
    a1 = fmaf(os[1][s], w, a1);
    a2 = fmaf(os[2][s], w, a2);
    a3 = fmaf(os[3][s], w, a3);
  }
  hs[0][tid] = silu_f(a0);
  hs[1][tid] = silu_f(a1);
  hs[2][tid] = silu_f(a2);
  hs[3][tid] = silu_f(a3);
  __syncthreads();
  int c = tid & 127, rg = tid >> 7;   // rows rg*2, rg*2+1
  const float* h0 = hs[rg * 2];
  const float* h1 = hs[rg * 2 + 1];
  float o0 = b4[c], o1 = b4[c];
  for (int k = 0; k < 256; k += 4) {
    float w0 = W4[(k + 0) * 128 + c];
    float w1 = W4[(k + 1) * 128 + c];
    float w2 = W4[(k + 2) * 128 + c];
    float w3 = W4[(k + 3) * 128 + c];
    float4 ha = *(const float4*)&h0[k];
    float4 hb = *(const float4*)&h1[k];
    o0 = fmaf(ha.w, w3, fmaf(ha.z, w2, fmaf(ha.y, w1, fmaf(ha.x, w0, o0))));
    o1 = fmaf(hb.w, w3, fmaf(hb.z, w2, fmaf(hb.y, w1, fmaf(hb.x, w0, o1))));
  }
  out[(b0 + rg * 2) * LATD + c]     = o0;
  out[(b0 + rg * 2 + 1) * LATD + c] = o1;
}

// ---------------- launcher ----------------

extern "C" void kernel_launch(void* const* d_in, const int* in_sizes, int n_in,
                              void* d_out, int out_size, void* d_ws, size_t ws_size,
                              hipStream_t stream) {
  const float* z_t  = (const float*)d_in[0];
  const float* t    = (const float*)d_in[1];
  const float* W1   = (const float*)d_in[2];
  const float* b1   = (const float*)d_in[3];
  const float* W2   = (const float*)d_in[4];
  const float* b2   = (const float*)d_in[5];
  const float* varp = (const float*)d_in[6];
  const float* A_p  = (const float*)d_in[7];
  // d_in[8] = B_p: imaginary part of H -> contributes 0 for real psi
  const float* D_p  = (const float*)d_in[9];
  const float* W3   = (const float*)d_in[10];
  const float* b3   = (const float*)d_in[11];
  const float* W4   = (const float*)d_in[12];
  const float* b4   = (const float*)d_in[13];
  float* out = (float*)d_out;

  int B = in_sizes[1];  // t has one element per batch row

  float* encc = (float*)d_ws;                 // B*40
  float* encs = encc + (size_t)B * 40;        // B*40
  float* obs  = encs + (size_t)B * 40;        // B*9
  float* varc = obs  + (size_t)B * 9;         // 60
  float* vars = varc + 64;                    // 60

  varcs_kernel<<<1, 64, 0, stream>>>(varp, varc, vars);
  enc_kernel<<<B / 4, 256, 0, stream>>>(z_t, t, W1, b1, W2, b2, encc, encs);
  circuit_kernel<<<B, 64, 0, stream>>>(encc, encs, varc, vars, A_p, D_p, obs);
  head_kernel<<<B / 4, 256, 0, stream>>>(obs, W3, b3, W4, b4, out);
}

// Round 3
// 128.831 us; speedup vs baseline: 1.2888x; 1.0253x over previous
//
#include <hip/hip_runtime.h>
#include <math.h>

#define NOBS 9
#define LATD 128

typedef unsigned u32x2 __attribute__((ext_vector_type(2)));

__device__ __forceinline__ float silu_f(float x) { return x / (1.f + expf(-x)); }

// ---------------- lane-exchange primitives ----------------

template<int CTRL>
__device__ __forceinline__ float dpp_perm(float x) {
  return __int_as_float(__builtin_amdgcn_update_dpp(0, __float_as_int(x), CTRL, 0xF, 0xF, true));
}
template<int PAT>
__device__ __forceinline__ float ds_swz(float x) {
  return __int_as_float(__builtin_amdgcn_ds_swizzle(__float_as_int(x), PAT));
}

// xor4: ds_swizzle xor-mask 4 (only remaining DS-pipe exchange)
__device__ __forceinline__ float x4(float x) { return ds_swz<0x101F>(x); }

#if __has_builtin(__builtin_amdgcn_permlane32_swap)
#define PL32 1
__device__ __forceinline__ float x32(float x, bool sel) {
  u32x2 r = __builtin_amdgcn_permlane32_swap(__float_as_uint(x), __float_as_uint(x), false, false);
  return __uint_as_float(sel ? r.x : r.y);
}
__device__ __forceinline__ float sum32(float x) {
  u32x2 r = __builtin_amdgcn_permlane32_swap(__float_as_uint(x), __float_as_uint(x), false, false);
  return __uint_as_float(r.x) + __uint_as_float(r.y);
}
#else
#define PL32 0
__device__ __forceinline__ float x32(float x, bool sel) { return __shfl_xor(x, 32, 64); }
__device__ __forceinline__ float sum32(float x) { return x + __shfl_xor(x, 32, 64); }
#endif

#if __has_builtin(__builtin_amdgcn_permlane16_swap)
#define PL16 1
__device__ __forceinline__ float x16(float x, bool sel) {
  u32x2 r = __builtin_amdgcn_permlane16_swap(__float_as_uint(x), __float_as_uint(x), false, false);
  return __uint_as_float(sel ? r.x : r.y);
}
__device__ __forceinline__ float sum16(float x) {
  u32x2 r = __builtin_amdgcn_permlane16_swap(__float_as_uint(x), __float_as_uint(x), false, false);
  return __uint_as_float(r.x) + __uint_as_float(r.y);
}
#else
#define PL16 0
__device__ __forceinline__ float x16(float x, bool sel) { return ds_swz<0x401F>(x); }
__device__ __forceinline__ float sum16(float x) { return x + ds_swz<0x401F>(x); }
#endif

__device__ __forceinline__ float wave_sum(float x) {
  x += dpp_perm<0xB1>(x);    // xor1
  x += dpp_perm<0x4E>(x);    // xor2
  x += x4(x);                // xor4
  x += dpp_perm<0x128>(x);   // xor8
  x = sum16(x);
  x = sum32(x);
  return x;
}

// ---------------- circuit gates ----------------
// amp index bits: [9:6] = reg bits 3..0 (qubits 0..3), [5:0] = lane bits (qubits 4..9)

template<int M>
__device__ __forceinline__ void ry_reg(float v[16], float c, float s) {
#pragma unroll
  for (int r = 0; r < 16; ++r) {
    if ((r & M) == 0) {
      float p0 = v[r], p1 = v[r | M];
      v[r]     = c * p0 - s * p1;
      v[r | M] = s * p0 + c * p1;
    }
  }
}

__device__ __forceinline__ void apply_rys(float v[16], int lane, bool sel32, bool sel16,
                                          const float* __restrict__ cc,
                                          const float* __restrict__ ss) {
  ry_reg<8>(v, cc[0], ss[0]);
  ry_reg<4>(v, cc[1], ss[1]);
  ry_reg<2>(v, cc[2], ss[2]);
  ry_reg<1>(v, cc[3], ss[3]);
  { float c = cc[4], s = ss[4], sp = (lane & 32) ? s : -s;   // q4: xor32
#pragma unroll
    for (int r = 0; r < 16; ++r) { float p = x32(v[r], sel32); v[r] = fmaf(c, v[r], sp * p); } }
  { float c = cc[5], s = ss[5], sp = (lane & 16) ? s : -s;   // q5: xor16
#pragma unroll
    for (int r = 0; r < 16; ++r) { float p = x16(v[r], sel16); v[r] = fmaf(c, v[r], sp * p); } }
  { float c = cc[6], s = ss[6], sp = (lane & 8) ? s : -s;    // q6: xor8 (DPP ror8)
#pragma unroll
    for (int r = 0; r < 16; ++r) { float p = dpp_perm<0x128>(v[r]); v[r] = fmaf(c, v[r], sp * p); } }
  { float c = cc[7], s = ss[7], sp = (lane & 4) ? s : -s;    // q7: xor4 (swizzle)
#pragma unroll
    for (int r = 0; r < 16; ++r) { float p = x4(v[r]); v[r] = fmaf(c, v[r], sp * p); } }
  { float c = cc[8], s = ss[8], sp = (lane & 2) ? s : -s;    // q8: xor2
#pragma unroll
    for (int r = 0; r < 16; ++r) { float p = dpp_perm<0x4E>(v[r]); v[r] = fmaf(c, v[r], sp * p); } }
  { float c = cc[9], s = ss[9], sp = (lane & 1) ? s : -s;    // q9: xor1
#pragma unroll
    for (int r = 0; r < 16; ++r) { float p = dpp_perm<0xB1>(v[r]); v[r] = fmaf(c, v[r], sp * p); } }
}

__device__ __forceinline__ void cnot_ladder(float v[16], int lane, bool sel32, bool sel16) {
  float t;
  // even phase: (0,1),(2,3) reg-reg; (4,5),(6,7),(8,9) lane-lane
  t=v[8];  v[8]=v[12];  v[12]=t;   // ctrl q0 (bit3) -> tgt q1 (bit2)
  t=v[9];  v[9]=v[13];  v[13]=t;
  t=v[10]; v[10]=v[14]; v[14]=t;
  t=v[11]; v[11]=v[15]; v[15]=t;
  t=v[2];  v[2]=v[3];   v[3]=t;    // ctrl q2 (bit1) -> tgt q3 (bit0)
  t=v[6];  v[6]=v[7];   v[7]=t;
  t=v[10]; v[10]=v[11]; v[11]=t;
  t=v[14]; v[14]=v[15]; v[15]=t;
  { bool c45 = (lane & 32);        // ctrl q4 -> tgt q5 (xor16)
#pragma unroll
    for (int r = 0; r < 16; ++r) { float p = x16(v[r], sel16); v[r] = c45 ? p : v[r]; } }
  { bool c67 = (lane & 8);         // ctrl q6 -> tgt q7 (xor4)
#pragma unroll
    for (int r = 0; r < 16; ++r) { float p = x4(v[r]); v[r] = c67 ? p : v[r]; } }
  { bool c89 = (lane & 2);         // ctrl q8 -> tgt q9 (xor1)
#pragma unroll
    for (int r = 0; r < 16; ++r) { float p = dpp_perm<0xB1>(v[r]); v[r] = c89 ? p : v[r]; } }
  // odd phase: (1,2) reg-reg; (3,4) reg-lane; (5,6),(7,8) lane-lane
  t=v[4];  v[4]=v[6];   v[6]=t;    // ctrl q1 (bit2) -> tgt q2 (bit1)
  t=v[5];  v[5]=v[7];   v[7]=t;
  t=v[12]; v[12]=v[14]; v[14]=t;
  t=v[13]; v[13]=v[15]; v[15]=t;
#pragma unroll
  for (int r = 1; r < 16; r += 2) v[r] = x32(v[r], sel32);  // ctrl q3 (reg bit0) -> tgt q4 (xor32)
  { bool c56 = (lane & 16);        // ctrl q5 -> tgt q6 (xor8)
#pragma unroll
    for (int r = 0; r < 16; ++r) { float p = dpp_perm<0x128>(v[r]); v[r] = c56 ? p : v[r]; } }
  { bool c78 = (lane & 4);         // ctrl q7 -> tgt q8 (xor2)
#pragma unroll
    for (int r = 0; r < 16; ++r) { float p = dpp_perm<0x4E>(v[r]); v[r] = c78 ? p : v[r]; } }
}

// ---------------- fused kernel: 4 batch rows per 256-thread block ----------------

__global__ __launch_bounds__(256) void fused_kernel(
    const float* __restrict__ z, const float* __restrict__ t,
    const float* __restrict__ W1, const float* __restrict__ b1,
    const float* __restrict__ W2, const float* __restrict__ b2,
    const float* __restrict__ varp,
    const float* __restrict__ A_p, const float* __restrict__ D_p,
    const float* __restrict__ W3, const float* __restrict__ b3,
    const float* __restrict__ W4, const float* __restrict__ b4,
    float* __restrict__ out) {
  __shared__ float xs[4][256];
  __shared__ float hs[4][256];
  __shared__ float dump[4][1024];
  __shared__ float cs[4][40], sn[4][40];
  __shared__ float vcs[60], vsn[60];
  __shared__ float os[4][NOBS];

  int tid = threadIdx.x;
  int b0 = blockIdx.x * 4;

  // var-layer cos/sin (redundant per block, trivial)
  if (tid < 60) {
    float s, c;
    sincosf(0.5f * varp[tid], &s, &c);
    vcs[tid] = c; vsn[tid] = s;
  }

  // ---- phase 1: build x = [z, cos(t f), sin(t f)] ----
#pragma unroll
  for (int r = 0; r < 4; ++r) {
    int b = b0 + r;
    if (tid < 128) {
      xs[r][tid] = z[b * 128 + tid];
    } else {
      int i = tid - 128, j = i & 63;
      float freq = expf(-9.2103403719761836f * (float)j * (1.f / 64.f));
      float arg = t[b] * freq;
      xs[r][tid] = (i < 64) ? cosf(arg) : sinf(arg);
    }
  }
  __syncthreads();

  // ---- phase 2: h = silu(x@W1 + b1)  (256 cols, 4 rows) ----
  {
    float bv = b1[tid];
    float a0 = bv, a1 = bv, a2 = bv, a3 = bv;
#pragma unroll 4
    for (int k = 0; k < 256; k += 4) {
      float w0 = W1[(k + 0) * 256 + tid];
      float w1 = W1[(k + 1) * 256 + tid];
      float w2 = W1[(k + 2) * 256 + tid];
      float w3 = W1[(k + 3) * 256 + tid];
      float4 x0 = *(const float4*)&xs[0][k];
      float4 x1 = *(const float4*)&xs[1][k];
      float4 x2 = *(const float4*)&xs[2][k];
      float4 x3 = *(const float4*)&xs[3][k];
      a0 = fmaf(x0.w, w3, fmaf(x0.z, w2, fmaf(x0.y, w1, fmaf(x0.x, w0, a0))));
      a1 = fmaf(x1.w, w3, fmaf(x1.z, w2, fmaf(x1.y, w1, fmaf(x1.x, w0, a1))));
      a2 = fmaf(x2.w, w3, fmaf(x2.z, w2, fmaf(x2.y, w1, fmaf(x2.x, w0, a2))));
      a3 = fmaf(x3.w, w3, fmaf(x3.z, w2, fmaf(x3.y, w1, fmaf(x3.x, w0, a3))));
    }
    hs[0][tid] = silu_f(a0);
    hs[1][tid] = silu_f(a1);
    hs[2][tid] = silu_f(a2);
    hs[3][tid] = silu_f(a3);
  }
  __syncthreads();

  // ---- phase 3: ang = h@W2 + b2 -> cos/sin(ang/2) ----
  if (tid < 160) {
    int r = tid / 40, c = tid - r * 40;
    float acc = b2[c];
#pragma unroll 4
    for (int k = 0; k < 256; k += 4) {
      float4 h = *(const float4*)&hs[r][k];
      acc = fmaf(h.x, W2[(k + 0) * 40 + c], acc);
      acc = fmaf(h.y, W2[(k + 1) * 40 + c], acc);
      acc = fmaf(h.z, W2[(k + 2) * 40 + c], acc);
      acc = fmaf(h.w, W2[(k + 3) * 40 + c], acc);
    }
    float s, cv;
    sincosf(0.5f * acc, &s, &cv);
    cs[r][c] = cv; sn[r][c] = s;
  }
  __syncthreads();

  // ---- phase 4: quantum circuit, wave w = batch row b0+w ----
  {
    int wave = tid >> 6;
    int lane = tid & 63;
    // runtime polarity probe for permlane swaps (uniform cost, correct under either HW polarity)
    bool sel32 = true, sel16 = true;
#if PL32
    { u32x2 tt = __builtin_amdgcn_permlane32_swap((unsigned)lane, (unsigned)lane, false, false);
      sel32 = (tt.x == (unsigned)(lane ^ 32)); }
#endif
#if PL16
    { u32x2 tt = __builtin_amdgcn_permlane16_swap((unsigned)lane, (unsigned)lane, false, false);
      sel16 = (tt.x == (unsigned)(lane ^ 16)); }
#endif
    const float* cc = cs[wave];
    const float* ss = sn[wave];

    // layer 0 on |0...0>: product state
    float base = 1.f;
    base *= (lane & 32) ? ss[4] : cc[4];
    base *= (lane & 16) ? ss[5] : cc[5];
    base *= (lane & 8)  ? ss[6] : cc[6];
    base *= (lane & 4)  ? ss[7] : cc[7];
    base *= (lane & 2)  ? ss[8] : cc[8];
    base *= (lane & 1)  ? ss[9] : cc[9];
    float v[16];
#pragma unroll
    for (int r = 0; r < 16; ++r) {
      float p = base;
      p *= (r & 8) ? ss[0] : cc[0];
      p *= (r & 4) ? ss[1] : cc[1];
      p *= (r & 2) ? ss[2] : cc[2];
      p *= (r & 1) ? ss[3] : cc[3];
      v[r] = p;
    }
    cnot_ladder(v, lane, sel32, sel16);
#pragma unroll 1
    for (int layer = 1; layer < 4; ++layer) {
      apply_rys(v, lane, sel32, sel16, cc + layer * 10, ss + layer * 10);
      if (layer < 3) cnot_ladder(v, lane, sel32, sel16);
    }
#pragma unroll 1
    for (int ly = 0; ly < 6; ++ly) {
      apply_rys(v, lane, sel32, sel16, vcs + ly * 10, vsn + ly * 10);
      cnot_ladder(v, lane, sel32, sel16);
    }

    float* sw = dump[wave];
#pragma unroll
    for (int r = 0; r < 16; ++r) sw[r * 64 + lane] = v[r];

    // expectation values (obs s acts on amp bits (9-s, 8-s))
#pragma unroll 1
    for (int s = 0; s < NOBS; ++s) {
      const int r8 = 8 - s;
      const int stride = 1 << r8;
      float h10 = A_p[s*6+0], h20 = A_p[s*6+1], h21 = A_p[s*6+2];
      float h30 = A_p[s*6+3], h31 = A_p[s*6+4], h32 = A_p[s*6+5];
      float d0 = 2.f * D_p[s*4+1], d1 = 2.f * D_p[s*4+2], d2 = 2.f * D_p[s*4+3];
      float acc = 0.f;
#pragma unroll
      for (int k = 0; k < 4; ++k) {
        int p = lane + 64 * k;
        int a  = p >> r8;
        int rr = p & (stride - 1);
        int bse = (a << (r8 + 2)) + rr;
        float x0 = sw[bse];
        float x1 = sw[bse + stride];
        float x2 = sw[bse + 2 * stride];
        float x3 = sw[bse + 3 * stride];
        acc += d0 * x0 * x0 + d1 * x1 * x1 + d2 * x2 * x2
             + 2.f * (h10 * x1 * x0 + h20 * x2 * x0 + h21 * x2 * x1
                    + h30 * x3 * x0 + h31 * x3 * x1 + h32 * x3 * x2);
      }
      acc = wave_sum(acc);
      if (lane == 0) os[wave][s] = acc;
    }
  }
  __syncthreads();

  // ---- phase 5: head: out = silu(obs@W3+b3) @ W4 + b4 ----
  {
    float bv = b3[tid];
    float a0 = bv, a1 = bv, a2 = bv, a3 = bv;
#pragma unroll
    for (int s = 0; s < NOBS; ++s) {
      float w = W3[s * 256 + tid];
      a0 = fmaf(os[0][s], w, a0);
      a1 = fmaf(os[1][s], w, a1);
      a2 = fmaf(os[2][s], w, a2);
      a3 = fmaf(os[3][s], w, a3);
    }
    hs[0][tid] = silu_f(a0);
    hs[1][tid] = silu_f(a1);
    hs[2][tid] = silu_f(a2);
    hs[3][tid] = silu_f(a3);
  }
  __syncthreads();
  {
    int c = tid & 127, rg = tid >> 7;   // rows rg*2, rg*2+1
    const float* h0 = hs[rg * 2];
    const float* h1 = hs[rg * 2 + 1];
    float o0 = b4[c], o1 = b4[c];
#pragma unroll 4
    for (int k = 0; k < 256; k += 4) {
      float w0 = W4[(k + 0) * 128 + c];
      float w1 = W4[(k + 1) * 128 + c];
      float w2 = W4[(k + 2) * 128 + c];
      float w3 = W4[(k + 3) * 128 + c];
      float4 ha = *(const float4*)&h0[k];
      float4 hb = *(const float4*)&h1[k];
      o0 = fmaf(ha.w, w3, fmaf(ha.z, w2, fmaf(ha.y, w1, fmaf(ha.x, w0, o0))));
      o1 = fmaf(hb.w, w3, fmaf(hb.z, w2, fmaf(hb.y, w1, fmaf(hb.x, w0, o1))));
    }
    out[(b0 + rg * 2) * LATD + c]     = o0;
    out[(b0 + rg * 2 + 1) * LATD + c] = o1;
  }
}

// ---------------- launcher ----------------

extern "C" void kernel_launch(void* const* d_in, const int* in_sizes, int n_in,
                              void* d_out, int out_size, void* d_ws, size_t ws_size,
                              hipStream_t stream) {
  const float* z_t  = (const float*)d_in[0];
  const float* t    = (const float*)d_in[1];
  const float* W1   = (const float*)d_in[2];
  const float* b1   = (const float*)d_in[3];
  const float* W2   = (const float*)d_in[4];
  const float* b2   = (const float*)d_in[5];
  const float* varp = (const float*)d_in[6];
  const float* A_p  = (const float*)d_in[7];
  // d_in[8] = B_p: imaginary part of H -> contributes 0 for real psi
  const float* D_p  = (const float*)d_in[9];
  const float* W3   = (const float*)d_in[10];
  const float* b3   = (const float*)d_in[11];
  const float* W4   = (const float*)d_in[12];
  const float* b4   = (const float*)d_in[13];
  float* out = (float*)d_out;

  int B = in_sizes[1];  // t has one element per batch row

  fused_kernel<<<B / 4, 256, 0, stream>>>(z_t, t, W1, b1, W2, b2, varp,
                                          A_p, D_p, W3, b3, W4, b4, out);
}